// Round 3
// baseline (9427.078 us; speedup 1.0000x reference)
//
#include <hip/hip_runtime.h>
#include <hip/hip_fp16.h>
#include <math.h>

#define B_   8
#define CH   64
#define H_   256
#define W_   256
#define NPIX (H_*W_)        // 65536
#define NIMG (B_*NPIX)      // 524288 per-channel count for BN

// ---------------------------------------------------------------------------
// helpers
// ---------------------------------------------------------------------------
// reflect index (jnp.pad mode='reflect', excludes edge): -1->1, 256->254
__device__ __forceinline__ int refl(int i) {
    if (i < 0)    return -i;
    if (i >= 256) return 510 - i;
    return i;
}

// xn = clip((x+1)*0.5, 1e-6, 1); blended = 0.6*xn + 0.4*xn^1.5
__device__ __forceinline__ float prep1(float v) {
    float xn = fminf(fmaxf((v + 1.0f) * 0.5f, 1e-6f), 1.0f);
    return 0.6f * xn + 0.4f * xn * sqrtf(xn);
}

__device__ __forceinline__ float toF(float v)  { return v; }
__device__ __forceinline__ float toF(__half v) { return __half2float(v); }

template<typename T> struct Pack4;
template<> struct Pack4<float> {
    typedef float4 VT;
    static __device__ __forceinline__ VT pack(float a, float b, float c, float d) {
        return make_float4(a, b, c, d);
    }
};
template<> struct Pack4<__half> {
    typedef uint2 VT;
    static __device__ __forceinline__ VT pack(float a, float b, float c, float d) {
        union { __half h[4]; uint2 u; } p;
        p.h[0] = __float2half(a); p.h[1] = __float2half(b);
        p.h[2] = __float2half(c); p.h[3] = __float2half(d);
        return p.u;
    }
};

// stats layout (in d_out, 256 floats): [0..127] accum (sum,sumsq per ch),
// [128..191] a[64], [192..255] b[64]
__global__ void init_ab_kernel(float* __restrict__ stats) {
    int c = threadIdx.x;            // 64 threads
    stats[2*c]     = 0.f;
    stats[2*c + 1] = 0.f;
    stats[128 + c] = 1.0f;
    stats[192 + c] = 0.0f;
}

// ---------------------------------------------------------------------------
// init conv: xpre computed inline from x (prep + 5x5 bilateral), then
// 1 -> 64 channels, 3x3 SAME(zero pad), ReLU
// ---------------------------------------------------------------------------
template<typename TOUT>
__global__ __launch_bounds__(256) void conv_init_kernel(
    const float* __restrict__ x, const float* __restrict__ wi,
    TOUT* __restrict__ h)
{
    __shared__ float s_bl[14][38];   // blended halo (reflect)
    __shared__ float s_xp[10][34];   // xpre tile (conv zero-pad)
    __shared__ float s_w[576];
    int bx = blockIdx.x;   // W/32 = 8
    int by = blockIdx.y;   // H/8  = 32
    int b  = blockIdx.z;   // 8
    int tid = threadIdx.x;
    const float* xb = x + b * NPIX;

    for (int i = tid; i < 14*38; i += 256) {
        int r = i / 38, c = i - r * 38;
        int gy = refl(by * 8 + r - 3), gx = refl(bx * 32 + c - 3);
        s_bl[r][c] = prep1(xb[gy * W_ + gx]);
    }
    for (int i = tid; i < 576; i += 256) s_w[i] = wi[i];
    __syncthreads();

    for (int i = tid; i < 10*34; i += 256) {
        int r = i / 34, c = i - r * 34;
        int gy = by * 8 + r - 1, gx = bx * 32 + c - 1;
        float v = 0.f;
        if (gy >= 0 && gy < H_ && gx >= 0 && gx < W_) {
            float ctr = s_bl[r + 2][c + 2];
            float num = 0.f, den = 0.f;
            #pragma unroll
            for (int dy = -2; dy <= 2; ++dy)
                #pragma unroll
                for (int dx = -2; dx <= 2; ++dx) {
                    float nb = s_bl[r + 2 + dy][c + 2 + dx];
                    float d  = nb - ctr;
                    float wgt = expf(-(float)(dy*dy + dx*dx) * 2e-4f - d * d * 200.0f);
                    num += wgt * nb;
                    den += wgt;
                }
            v = num / den;
        }
        s_xp[r][c] = v;
    }
    __syncthreads();

    int px = tid & 31, py = tid >> 5;
    float v[9];
    #pragma unroll
    for (int dr = 0; dr < 3; ++dr)
        #pragma unroll
        for (int dc = 0; dc < 3; ++dc)
            v[dr*3+dc] = s_xp[py + dr][px + dc];

    int gy = by * 8 + py, gx = bx * 32 + px;
    TOUT* outp = h + (size_t)b * CH * NPIX + gy * W_ + gx;
    for (int oc = 0; oc < 64; ++oc) {
        float acc = 0.f;
        #pragma unroll
        for (int t = 0; t < 9; ++t) acc = fmaf(s_w[oc*9 + t], v[t], acc);
        float r = fmaxf(acc, 0.f);
        if (sizeof(TOUT) == 4) outp[(size_t)oc * NPIX] = (TOUT)r;
        else                   outp[(size_t)oc * NPIX] = (TOUT)__float2half(r);
    }
}

// ---------------------------------------------------------------------------
// body conv: 64 -> 64, pre-op relu(a*x+b) fused on input load,
// conv 3x3 SAME, ReLU, store, accumulate BN sum/sumsq (fp32 atomics).
// tile 32x16 px x 16 oc; thread = 4 px x 8 oc; ic chunked by 8.
// ---------------------------------------------------------------------------
template<typename TIN, typename TOUT>
__global__ __launch_bounds__(256) void conv_body_kernel(
    const TIN* __restrict__ hin, const float* __restrict__ wl,
    float* stats, TOUT* __restrict__ hout)
{
    __shared__ float s_in[8][18][34];    // 19584 B
    __shared__ float s_w[16][8][9];      //  4608 B
    __shared__ float s_red[4][8][2];     //   256 B

    const float* ab = stats + 128;

    int bx = blockIdx.x;            // W/32 = 8
    int by = blockIdx.y;            // H/16 = 16
    int bz = blockIdx.z;            // B*4  = 32
    int b       = bz >> 2;
    int oc_base = (bz & 3) * 16;
    int tid = threadIdx.x;
    int half = tid >> 7;            // 0/1 -> local oc sub-base half*8
    int pid  = tid & 127;
    int prow = pid >> 3;            // 0..15
    int pcol = (pid & 7) << 2;      // 0,4,..,28

    float acc[8][4];
    #pragma unroll
    for (int o = 0; o < 8; ++o)
        #pragma unroll
        for (int p = 0; p < 4; ++p) acc[o][p] = 0.f;

    const float* wbase = wl + oc_base * 576;   // [16 oc][64 ic][9]

    for (int ck = 0; ck < 8; ++ck) {
        // stage input tile: 8 ic x 18 x 34 with fused relu(a*x+b), zero pad
        for (int i = tid; i < 8*18*34; i += 256) {
            int ic  = i / 612;
            int rem = i - ic * 612;
            int r   = rem / 34;
            int cc  = rem - r * 34;
            int icg = ck * 8 + ic;
            int gy = by * 16 + r - 1, gx = bx * 32 + cc - 1;
            float v = 0.f;
            if (gy >= 0 && gy < H_ && gx >= 0 && gx < W_) {
                v = toF(hin[((size_t)b * CH + icg) * NPIX + gy * W_ + gx]);
                v = fmaxf(fmaf(v, ab[icg], ab[64 + icg]), 0.f);
            }
            s_in[ic][r][cc] = v;
        }
        // stage weights: 16 oc x 8 ic x 9
        float* swf = &s_w[0][0][0];
        for (int i = tid; i < 1152; i += 256) {
            int oc = i / 72;
            int rr = i - oc * 72;
            swf[i] = wbase[oc * 576 + ck * 72 + rr];
        }
        __syncthreads();

        #pragma unroll 2
        for (int ic = 0; ic < 8; ++ic) {
            float v[3][6];
            #pragma unroll
            for (int dr = 0; dr < 3; ++dr)
                #pragma unroll
                for (int j = 0; j < 6; ++j)
                    v[dr][j] = s_in[ic][prow + dr][pcol + j];
            #pragma unroll
            for (int o = 0; o < 8; ++o) {
                const float* wp = &s_w[half * 8 + o][ic][0];
                #pragma unroll
                for (int dr = 0; dr < 3; ++dr)
                    #pragma unroll
                    for (int dc = 0; dc < 3; ++dc) {
                        float wv = wp[dr*3 + dc];
                        #pragma unroll
                        for (int p = 0; p < 4; ++p)
                            acc[o][p] = fmaf(wv, v[dr][dc + p], acc[o][p]);
                    }
            }
        }
        __syncthreads();
    }

    // epilogue: ReLU, vector store, BN partial sums in fp32
    int gy  = by * 16 + prow;
    int gx0 = bx * 32 + pcol;
    float s1[8], s2[8];
    #pragma unroll
    for (int o = 0; o < 8; ++o) {
        float a0 = fmaxf(acc[o][0], 0.f);
        float a1 = fmaxf(acc[o][1], 0.f);
        float a2 = fmaxf(acc[o][2], 0.f);
        float a3 = fmaxf(acc[o][3], 0.f);
        int oc = oc_base + half * 8 + o;
        typename Pack4<TOUT>::VT pk = Pack4<TOUT>::pack(a0, a1, a2, a3);
        *reinterpret_cast<typename Pack4<TOUT>::VT*>(
            hout + ((size_t)b * CH + oc) * NPIX + gy * W_ + gx0) = pk;
        s1[o] = a0 + a1 + a2 + a3;
        s2[o] = a0*a0 + a1*a1 + a2*a2 + a3*a3;
    }
    #pragma unroll
    for (int o = 0; o < 8; ++o) {
        #pragma unroll
        for (int off = 32; off >= 1; off >>= 1) {
            s1[o] += __shfl_xor(s1[o], off);
            s2[o] += __shfl_xor(s2[o], off);
        }
    }
    int lane = tid & 63, wv = tid >> 6;
    if (lane == 0) {
        #pragma unroll
        for (int o = 0; o < 8; ++o) { s_red[wv][o][0] = s1[o]; s_red[wv][o][1] = s2[o]; }
    }
    __syncthreads();
    if (tid < 32) {
        int oc16 = tid >> 1, st = tid & 1;
        int wb = (oc16 >> 3) << 1;
        int o  = oc16 & 7;
        float vsum = s_red[wb][o][st] + s_red[wb + 1][o][st];
        atomicAdd(&stats[(oc_base + oc16) * 2 + st], vsum);
    }
}

// ---------------------------------------------------------------------------
// BN finalize: a = gamma*rsqrt(var+eps); b = beta - mean*a; re-zero accum.
// Optionally mirrors (a,b) into abf (dead h-buffer) for the final conv.
// ---------------------------------------------------------------------------
__global__ void bn_finalize_kernel(float* __restrict__ stats,
                                   const float* __restrict__ gamma,
                                   const float* __restrict__ beta,
                                   float* __restrict__ abf)
{
    int c = threadIdx.x;   // 64
    float sum   = stats[2*c];
    float sumsq = stats[2*c+1];
    const float invN = 1.0f / (float)NIMG;
    float mean = sum * invN;
    float var  = sumsq * invN - mean * mean;
    float a  = gamma[c] / sqrtf(var + 1e-5f);
    float bb = beta[c] - mean * a;
    stats[128 + c] = a;
    stats[192 + c] = bb;
    stats[2*c]   = 0.f;
    stats[2*c+1] = 0.f;
    if (abf) { abf[c] = a; abf[64 + c] = bb; }
}

// ---------------------------------------------------------------------------
// final conv: 64 -> 1 with input pre-op relu(a*x+b); out = xpre - noise
// xpre recomputed inline from x.
// ---------------------------------------------------------------------------
template<typename TIN>
__global__ __launch_bounds__(256) void conv_final_kernel(
    const TIN* __restrict__ hin, const float* __restrict__ wf,
    const float* __restrict__ abf, const float* __restrict__ x,
    float* __restrict__ out)
{
    __shared__ float s_bl[12][36];
    __shared__ float s_in[8][10][34];
    __shared__ float s_w[576];
    int bx = blockIdx.x;   // 8
    int by = blockIdx.y;   // 32
    int b  = blockIdx.z;   // 8
    int tid = threadIdx.x;
    const float* xb = x + b * NPIX;

    for (int i = tid; i < 12*36; i += 256) {
        int r = i / 36, c = i - r * 36;
        int gy = refl(by * 8 + r - 2), gx = refl(bx * 32 + c - 2);
        s_bl[r][c] = prep1(xb[gy * W_ + gx]);
    }
    for (int i = tid; i < 576; i += 256) s_w[i] = wf[i];
    __syncthreads();

    int px = tid & 31, py = tid >> 5;
    float ctr = s_bl[py + 2][px + 2];
    float num = 0.f, den = 0.f;
    #pragma unroll
    for (int dy = -2; dy <= 2; ++dy)
        #pragma unroll
        for (int dx = -2; dx <= 2; ++dx) {
            float nb = s_bl[py + 2 + dy][px + 2 + dx];
            float d  = nb - ctr;
            float wgt = expf(-(float)(dy*dy + dx*dx) * 2e-4f - d * d * 200.0f);
            num += wgt * nb;
            den += wgt;
        }
    float xpre = num / den;

    float acc = 0.f;
    for (int ck = 0; ck < 8; ++ck) {
        __syncthreads();
        for (int i = tid; i < 8*10*34; i += 256) {
            int ic  = i / 340;
            int rem = i - ic * 340;
            int r   = rem / 34;
            int cc  = rem - r * 34;
            int icg = ck * 8 + ic;
            int gy = by * 8 + r - 1, gx = bx * 32 + cc - 1;
            float v = 0.f;
            if (gy >= 0 && gy < H_ && gx >= 0 && gx < W_) {
                v = toF(hin[((size_t)b * CH + icg) * NPIX + gy * W_ + gx]);
                v = fmaxf(fmaf(v, abf[icg], abf[64 + icg]), 0.f);
            }
            s_in[ic][r][cc] = v;
        }
        __syncthreads();
        #pragma unroll
        for (int ic = 0; ic < 8; ++ic)
            #pragma unroll
            for (int dr = 0; dr < 3; ++dr)
                #pragma unroll
                for (int dc = 0; dc < 3; ++dc)
                    acc = fmaf(s_w[(ck*8 + ic)*9 + dr*3 + dc],
                               s_in[ic][py + dr][px + dc], acc);
    }

    int gy = by * 8 + py, gx = bx * 32 + px;
    out[b * NPIX + gy * W_ + gx] = xpre - acc;
}

// ---------------------------------------------------------------------------
// launcher — adaptive storage precision based on ws_size:
//   tier 0 (ws >= 256 MiB):      fp32 + fp32 ping-pong (exact fit)
//   tier 1 (ws >= 192 MiB):      fp32 + fp16
//   tier 2 (else, >= 128 MiB):   fp16 + fp16
// BN stats/affine live in d_out[0..255] (overwritten by conv_final at end);
// the layer-15 affine pair is parked in the dead h-buffer for conv_final.
// ---------------------------------------------------------------------------
extern "C" void kernel_launch(void* const* d_in, const int* in_sizes, int n_in,
                              void* d_out, int out_size, void* d_ws, size_t ws_size,
                              hipStream_t stream)
{
    const float* x        = (const float*)d_in[0];
    const float* w_init   = (const float*)d_in[1];
    const float* w_body   = (const float*)d_in[2];
    const float* bn_gamma = (const float*)d_in[3];
    const float* bn_beta  = (const float*)d_in[4];
    const float* w_final  = (const float*)d_in[5];
    float* out   = (float*)d_out;
    float* stats = (float*)d_out;    // 256 floats of scratch inside d_out

    char* wsb = (char*)d_ws;
    const size_t F32B = 134217728ULL;   // (8,64,256,256) fp32
    const size_t F16B = 67108864ULL;    // (8,64,256,256) fp16

    dim3 gInit(8, 32, 8), gBody(8, 16, 32), gFin(8, 32, 8);

    init_ab_kernel<<<1, 64, 0, stream>>>(stats);

    if (ws_size >= 2 * F32B) {
        // tier 0: fp32/fp32
        float* A = (float*)wsb;
        float* B = (float*)(wsb + F32B);
        conv_init_kernel<float><<<gInit, 256, 0, stream>>>(x, w_init, A);
        float* cur = A; float* nxt = B; float* abf = nullptr;
        for (int l = 0; l < 15; ++l) {
            conv_body_kernel<float, float><<<gBody, 256, 0, stream>>>(
                cur, w_body + (size_t)l * 36864, stats, nxt);
            bn_finalize_kernel<<<1, 64, 0, stream>>>(
                stats, bn_gamma + l * 64, bn_beta + l * 64,
                (l == 14) ? cur : nullptr);
            if (l == 14) abf = cur;
            float* t = cur; cur = nxt; nxt = t;
        }
        conv_final_kernel<float><<<gFin, 256, 0, stream>>>(cur, w_final, abf, x, out);
    } else if (ws_size >= F32B + F16B) {
        // tier 1: A fp32, B fp16; even layers read B write A, odd the reverse
        float*  A = (float*)wsb;
        __half* B = (__half*)(wsb + F32B);
        conv_init_kernel<__half><<<gInit, 256, 0, stream>>>(x, w_init, B);
        for (int l = 0; l < 15; ++l) {
            if ((l & 1) == 0)
                conv_body_kernel<__half, float><<<gBody, 256, 0, stream>>>(
                    B, w_body + (size_t)l * 36864, stats, A);
            else
                conv_body_kernel<float, __half><<<gBody, 256, 0, stream>>>(
                    A, w_body + (size_t)l * 36864, stats, B);
            bn_finalize_kernel<<<1, 64, 0, stream>>>(
                stats, bn_gamma + l * 64, bn_beta + l * 64,
                (l == 14) ? (float*)B : nullptr);
        }
        // l=14 is even: wrote A; B is dead and holds abf
        conv_final_kernel<float><<<gFin, 256, 0, stream>>>(A, w_final, (float*)B, x, out);
    } else {
        // tier 2: fp16/fp16
        __half* A = (__half*)wsb;
        __half* B = (__half*)(wsb + F16B);
        conv_init_kernel<__half><<<gInit, 256, 0, stream>>>(x, w_init, A);
        __half* cur = A; __half* nxt = B; float* abf = nullptr;
        for (int l = 0; l < 15; ++l) {
            conv_body_kernel<__half, __half><<<gBody, 256, 0, stream>>>(
                cur, w_body + (size_t)l * 36864, stats, nxt);
            bn_finalize_kernel<<<1, 64, 0, stream>>>(
                stats, bn_gamma + l * 64, bn_beta + l * 64,
                (l == 14) ? (float*)cur : nullptr);
            if (l == 14) abf = (float*)cur;
            __half* t = cur; cur = nxt; nxt = t;
        }
        conv_final_kernel<__half><<<gFin, 256, 0, stream>>>(cur, w_final, abf, x, out);
    }
}